// Round 10
// baseline (2284.734 us; speedup 1.0000x reference)
//
#include <hip/hip_runtime.h>

#define NPN   1024            // nodes per slice
#define NB    512             // batch (slices)
#define NE_S  2048            // edges per slice
#define DD    128             // feature dim
#define NN    (NB * NPN)      // 524288 total nodes
#define NE    (NB * NE_S)     // 1048576 total edges

typedef short s16x8 __attribute__((ext_vector_type(8)));
typedef float f32x4 __attribute__((ext_vector_type(4)));

static __device__ __forceinline__ unsigned short f2bf(float f) {
    unsigned u = __builtin_bit_cast(unsigned, f);
    unsigned r = (u + 0x7FFFu + ((u >> 16) & 1u)) >> 16;   // RNE
    return (unsigned short)r;
}
static __device__ __forceinline__ float bf2f(unsigned short h) {
    unsigned u = ((unsigned)h) << 16;
    return __builtin_bit_cast(float, u);
}

// ---------- CSR / degree precompute (layer-invariant) ----------

__global__ void k_count(const int* __restrict__ ei, int* __restrict__ deg) {
    int t = blockIdx.x * 256 + threadIdx.x;          // 0..NE-1
    int b = t >> 11, e = t & (NE_S - 1);
    int col = ei[b * (2 * NE_S) + NE_S + e];
    atomicAdd(&deg[b * NPN + col], 1);
}

__global__ void k_dinv(const int* __restrict__ deg, float* __restrict__ dinv) {
    int i = blockIdx.x * 256 + threadIdx.x;
    dinv[i] = rsqrtf((float)(deg[i] + 1));           // +1 self-loop
}

__global__ __launch_bounds__(1024) void k_scan(const int* __restrict__ deg,
                                               int* __restrict__ coff,
                                               int* __restrict__ cur) {
    __shared__ int s[NPN];
    int b = blockIdx.x, t = threadIdx.x;
    int v = deg[b * NPN + t];
    s[t] = v;
    __syncthreads();
    for (int off = 1; off < NPN; off <<= 1) {
        int add = (t >= off) ? s[t - off] : 0;
        __syncthreads();
        s[t] += add;
        __syncthreads();
    }
    coff[b * NPN + t] = b * NE_S + (s[t] - v);       // exclusive prefix, global offset
    cur[b * NPN + t] = 0;
}

// packed edge meta: .x = src_local | (dst_local<<16), .y = bitcast(norm)
__global__ void k_fill(const int* __restrict__ ei, const float* __restrict__ dinv,
                       const int* __restrict__ coff, int* __restrict__ cur,
                       int2* __restrict__ cmeta) {
    int t = blockIdx.x * 256 + threadIdx.x;
    int b = t >> 11, e = t & (NE_S - 1);
    int r = ei[b * (2 * NE_S) + e];
    int c = ei[b * (2 * NE_S) + NE_S + e];
    int gr = b * NPN + r, gc = b * NPN + c;
    int pos = coff[gc] + atomicAdd(&cur[gc], 1);
    float nw = dinv[gr] * dinv[gc];
    cmeta[pos] = make_int2(r | (c << 16), __builtin_bit_cast(int, nw));
}

// ---------- W pre-transpose + bf16 hi/lo split (per layer, tiny) ----------

__global__ __launch_bounds__(256) void k_wsplit(const float* __restrict__ W,
                                                short* __restrict__ WTh,
                                                short* __restrict__ WTl) {
    int idx = blockIdx.x * 256 + threadIdx.x;        // 0..16383
    int k = idx >> 7, n = idx & 127;
    float f = W[idx];
    unsigned short h = f2bf(f);
    unsigned short l = f2bf(f - bf2f(h));
    WTh[n * DD + k] = (short)h;
    WTl[n * DD + k] = (short)l;
}

// ---------- fused GCN layer: out = relu((A_hat x) @ W + b) ----------
// 512 thr / 8 waves / block; 64x128 tile; 32 KiB LDS union; 4 blocks/CU.
// PAIRED gather: lanes 0-31 fetch edge A's row (float4/lane), lanes 32-63
// edge B's -> ONE vmem instruction per 2 edges (halves the per-CU request
// count, the r9-identified bottleneck). Meta via uniform readlane pairs +
// per-half cndmask (scalar-friendly, no LDS in address chain). Per-edge
// LDS atomics (4/lane) replace run accumulation. sAcc is plain [row][feat].
// B fragments loaded per-ks inside MFMA loop: peak VGPR < 64, no spills.

__global__ __launch_bounds__(512, 8) void k_layer(const float* __restrict__ x,
                                                  unsigned gmask,
                                                  const short* __restrict__ WTh,
                                                  const short* __restrict__ WTl,
                                                  const float* __restrict__ bias,
                                                  const float* __restrict__ dinv,
                                                  const int* __restrict__ coff,
                                                  const int2* __restrict__ cmeta,
                                                  float* __restrict__ out) {
    __shared__ float sBuf[64 * DD];      // 32 KiB union
    float* sAcc = sBuf;
    char*  sH   = (char*)sBuf;           // after repack: hi bytes [0,16K)
    char*  sL   = (char*)sBuf + 16384;   // lo bytes [16K,32K)

    int t = threadIdx.x;
    int wave = t >> 6, lane = t & 63;
    int half = lane >> 5, li = lane & 31;
    // XCD-aware swizzle: 8192 blocks = 8 XCDs x 1024; 16 consecutive
    // blocks (one slice) land on one XCD -> slice rows L2-hit.
    int wb = (int)((blockIdx.x & 7) * 1024 + (blockIdx.x >> 3));
    int m0 = wb * 64;
    int sbase = (wb >> 4) << 10;         // slice base node

    int n  = lane & 15;
    int kq = lane >> 4;

    // wave's CSR range (scalarized -> uniform control flow)
    int r0g = m0 + wave * 8;
    int wlo = (m0 - sbase) + wave * 8;   // slice-local first row of this wave
    int eBeg = __builtin_amdgcn_readfirstlane(coff[r0g]);
    int eEnd = __builtin_amdgcn_readfirstlane((r0g + 8 < NN) ? coff[r0g + 8] : NE);

    // ---- first meta chunk: issue EARLY so it overlaps self-init ----
    int c0 = eBeg;
    int nC0 = eEnd - c0; nC0 = nC0 > 64 ? 64 : nC0;
    int2 md = make_int2((int)0xFFFF0000u, 0);
    if (lane < nC0) md = cmeta[c0 + lane];

    // ---- self-loop init: paired rows, float4/lane, plain [row][feat] ----
    #pragma unroll
    for (int i = 0; i < 4; ++i) {
        int row = wave * 8 + 2 * i + half;
        int g = m0 + row;
        float dv = dinv[g];
        f32x4 v = *(const f32x4*)&x[(size_t)((unsigned)g & gmask) * DD + li * 4];
        f32x4 sv;
        sv[0] = dv * dv * v[0]; sv[1] = dv * dv * v[1];
        sv[2] = dv * dv * v[2]; sv[3] = dv * dv * v[3];
        *(f32x4*)&sAcc[row * DD + li * 4] = sv;
    }
    // no barrier needed: this wave only touches its own 8 rows below

    // ---- edge walk: paired loads (2 edges / vmem instr), per-edge atomics ----
    int nC = nC0;
    while (true) {
        int nB = (nC + 15) & ~15;
        for (int b0 = 0; b0 < nB; b0 += 16) {
            f32x4 v[8]; int mdx[8]; float wv[8];
            #pragma unroll
            for (int p = 0; p < 8; ++p) {
                int sA = __builtin_amdgcn_readlane(md.x, b0 + 2 * p);
                int sB = __builtin_amdgcn_readlane(md.x, b0 + 2 * p + 1);
                int wA = __builtin_amdgcn_readlane(md.y, b0 + 2 * p);
                int wB = __builtin_amdgcn_readlane(md.y, b0 + 2 * p + 1);
                mdx[p] = half ? sB : sA;
                wv[p]  = __builtin_bit_cast(float, half ? wB : wA);
                int src = sbase + (mdx[p] & 0xFFFF);
                v[p] = *(const f32x4*)&x[(size_t)((unsigned)src & gmask) * DD + li * 4];
            }
            #pragma unroll
            for (int p = 0; p < 8; ++p) {
                unsigned rl = (((unsigned)mdx[p]) >> 16) - (unsigned)wlo;
                if (rl < 8u) {
                    float* ap = &sAcc[(wave * 8 + (int)rl) * DD + li * 4];
                    atomicAdd(&ap[0], wv[p] * v[p][0]);
                    atomicAdd(&ap[1], wv[p] * v[p][1]);
                    atomicAdd(&ap[2], wv[p] * v[p][2]);
                    atomicAdd(&ap[3], wv[p] * v[p][3]);
                }
            }
        }
        c0 += 64;
        if (c0 >= eEnd) break;
        nC = eEnd - c0; nC = nC > 64 ? 64 : nC;
        md = make_int2((int)0xFFFF0000u, 0);
        if (lane < nC) md = cmeta[c0 + lane];
    }
    __syncthreads();

    // ---- in-place repack: fp32 -> bf16 hi/lo, XOR-swizzled ----
    // plain layout: lane reads feats (2*lane, 2*lane+1) as float2 (2-way = free)
    float fe[8], fo[8];
    #pragma unroll
    for (int i = 0; i < 8; ++i) {
        int row = wave * 8 + i;
        float2 p2 = *(const float2*)&sAcc[row * DD + lane * 2];
        fe[i] = p2.x; fo[i] = p2.y;
    }
    __syncthreads();
    #pragma unroll
    for (int i = 0; i < 8; ++i) {
        int row = wave * 8 + i;
        unsigned short hx = f2bf(fe[i]); unsigned short lx = f2bf(fe[i] - bf2f(hx));
        unsigned short hy = f2bf(fo[i]); unsigned short ly = f2bf(fo[i] - bf2f(hy));
        unsigned bo = ((unsigned)row * 256u + (unsigned)lane * 4u) ^ ((unsigned)(row & 7) << 4);
        *(unsigned*)(sH + bo) = ((unsigned)hy << 16) | hx;
        *(unsigned*)(sL + bo) = ((unsigned)ly << 16) | lx;
    }
    __syncthreads();

    // ---- MFMA phase: wave strip = rows 0..63, cols wave*16..+15 ----
    // B fragments loaded per-ks (8 VGPRs live, L2-resident 64 KB table)
    f32x4 acc[4];
    #pragma unroll
    for (int m = 0; m < 4; ++m) acc[m] = (f32x4){0.f, 0.f, 0.f, 0.f};

    const short* bhp = &WTh[(wave * 16 + n) * DD + kq * 8];
    const short* blp = &WTl[(wave * 16 + n) * DD + kq * 8];
    #pragma unroll
    for (int ks = 0; ks < 4; ++ks) {
        s16x8 bhv = *(const s16x8*)(bhp + ks * 32);
        s16x8 blv = *(const s16x8*)(blp + ks * 32);
        #pragma unroll
        for (int m = 0; m < 4; ++m) {
            int row = m * 16 + n;
            unsigned bo = ((unsigned)row * 256u + (unsigned)(ks * 64 + kq * 16))
                          ^ ((unsigned)(row & 7) << 4);
            s16x8 ah = *(const s16x8*)(sH + bo);
            s16x8 al = *(const s16x8*)(sL + bo);
            acc[m] = __builtin_amdgcn_mfma_f32_16x16x32_bf16(ah, bhv, acc[m], 0, 0, 0);
            acc[m] = __builtin_amdgcn_mfma_f32_16x16x32_bf16(ah, blv, acc[m], 0, 0, 0);
            acc[m] = __builtin_amdgcn_mfma_f32_16x16x32_bf16(al, bhv, acc[m], 0, 0, 0);
        }
    }

    // ---- direct epilogue: bias + relu; C/D layout col=lane&15, row=kq*4+reg ----
    int col = wave * 16 + n;
    float bv = bias[col];
    #pragma unroll
    for (int m = 0; m < 4; ++m) {
        #pragma unroll
        for (int r = 0; r < 4; ++r) {
            int row = m * 16 + kq * 4 + r;
            float vv = acc[m][r] + bv;
            out[(size_t)(m0 + row) * DD + col] = fmaxf(vv, 0.f);
        }
    }
}

// ---------- launch ----------

extern "C" void kernel_launch(void* const* d_in, const int* in_sizes, int n_in,
                              void* d_out, int out_size, void* d_ws, size_t ws_size,
                              hipStream_t stream) {
    const int*   ei  = (const int*)d_in[0];
    const float* emb = (const float*)d_in[1];
    const float* W1  = (const float*)d_in[2];
    const float* b1  = (const float*)d_in[3];
    const float* W2  = (const float*)d_in[4];
    const float* b2  = (const float*)d_in[5];
    const float* W3  = (const float*)d_in[6];
    const float* b3  = (const float*)d_in[7];
    float* out = (float*)d_out;

    float* x_mid = (float*)d_ws;                       // NN*DD floats (256 MiB)
    float* dinv  = x_mid + (size_t)NN * DD;
    int*   deg   = (int*)(dinv + NN);
    int*   coff  = deg + NN;
    int*   cur   = coff + NN;
    int2*  cmeta = (int2*)(cur + NN);                  // NE int2 (8 MiB)
    short* WTh1  = (short*)(cmeta + NE);
    short* WTl1  = WTh1 + DD * DD;
    short* WTh2  = WTl1 + DD * DD;
    short* WTl2  = WTh2 + DD * DD;
    short* WTh3  = WTl2 + DD * DD;
    short* WTl3  = WTh3 + DD * DD;

    hipMemsetAsync(deg, 0, NN * sizeof(int), stream);
    k_count<<<NE / 256, 256, 0, stream>>>(ei, deg);
    k_dinv<<<NN / 256, 256, 0, stream>>>(deg, dinv);
    k_scan<<<NB, NPN, 0, stream>>>(deg, coff, cur);
    k_fill<<<NE / 256, 256, 0, stream>>>(ei, dinv, coff, cur, cmeta);

    k_wsplit<<<64, 256, 0, stream>>>(W1, WTh1, WTl1);
    k_wsplit<<<64, 256, 0, stream>>>(W2, WTh2, WTl2);
    k_wsplit<<<64, 256, 0, stream>>>(W3, WTh3, WTl3);

    // layer 1: x = tiled emb (gmask folds node id onto the 1024-row table)
    k_layer<<<NN / 64, 512, 0, stream>>>(emb, NPN - 1, WTh1, WTl1, b1,
                                         dinv, coff, cmeta, out);
    // layer 2: out -> x_mid
    k_layer<<<NN / 64, 512, 0, stream>>>(out, 0xFFFFFFFFu, WTh2, WTl2, b2,
                                         dinv, coff, cmeta, x_mid);
    // layer 3: x_mid -> out
    k_layer<<<NN / 64, 512, 0, stream>>>(x_mid, 0xFFFFFFFFu, WTh3, WTl3, b3,
                                         dinv, coff, cmeta, out);
}